// Round 15
// baseline (225.482 us; speedup 1.0000x reference)
//
#include <hip/hip_runtime.h>

#define NB 32768
#define DD 16
#define HH 64
#define EPB 16

typedef __attribute__((ext_vector_type(8))) short short8;
typedef __attribute__((ext_vector_type(2))) float f32x2;
typedef __attribute__((ext_vector_type(4))) float f32x4;
typedef __attribute__((ext_vector_type(4))) unsigned uint4v;

union Frag { short8 s; uint4v u; unsigned d[4]; };

struct Params {
  const float *ts, *x0;
  const float *W0,*b0,*g0,*gb0,*hb0;
  const float *W1,*b1,*g1,*gb1,*hb1;
  const float *W2,*b2,*g2,*gb2,*hb2;
  const float *W3,*b3,*g3,*gb3,*hb3;
  float *out;
};

__device__ __forceinline__ float bfs(unsigned short u){
  return __uint_as_float(((unsigned)u)<<16);
}
__device__ __forceinline__ unsigned short f2bf(float f){   // full RNE (init only)
  unsigned u=__float_as_uint(f);
  return (unsigned short)((u + 0x7FFFu + ((u>>16)&1u))>>16);
}
__device__ __forceinline__ unsigned pk2bf(float lo, float hi){
  unsigned a=__float_as_uint(lo)+0x8000u;
  unsigned b=__float_as_uint(hi)+0x8000u;
  return __builtin_amdgcn_perm(b, a, 0x07060302u);
}
__device__ __forceinline__ unsigned short f2bf1(float f){
  return (unsigned short)((__float_as_uint(f)+0x8000u)>>16);
}
__device__ __forceinline__ float sigm(float u){
  return __builtin_amdgcn_rcpf(1.0f+__builtin_amdgcn_exp2f(-1.44269504f*u));
}
#define WV() __builtin_amdgcn_wave_barrier()
#define SB0() __builtin_amdgcn_sched_barrier(0)
#define MFMA(A,B,C) __builtin_amdgcn_mfma_f32_16x16x32_bf16((A),(B),(C),0,0,0)

// unified epilogue: h -> bf16 (stride 72), s -> f32 (stride 76, conflict-free)
__device__ __forceinline__ void fwd_epi0(const f32x4& c, float tcur,
    const float4 sc,
    unsigned short* __restrict__ hdst, float* __restrict__ sdstf,
    int jw, int q)
{
  const float gate = sigm(tcur*sc.x+sc.y);
  const float gk   = gate*2.88539008f;
  const float tbk  = (tcur*sc.z)*2.88539008f;
  const float g4   = 4.0f*gate;
  const f32x2 c01={c[0],c[1]}, c23={c[2],c[3]};
  const f32x2 pre01 = c01*gk + tbk;
  const f32x2 pre23 = c23*gk + tbk;
  const f32x2 e01={__builtin_amdgcn_exp2f(pre01[0]),__builtin_amdgcn_exp2f(pre01[1])};
  const f32x2 e23={__builtin_amdgcn_exp2f(pre23[0]),__builtin_amdgcn_exp2f(pre23[1])};
  const f32x2 d01=e01+1.0f, d23=e23+1.0f;
  const f32x2 rc01={__builtin_amdgcn_rcpf(d01[0]),__builtin_amdgcn_rcpf(d01[1])};
  const f32x2 rc23={__builtin_amdgcn_rcpf(d23[0]),__builtin_amdgcn_rcpf(d23[1])};
  const f32x2 th01 = rc01*-2.0f + 1.0f;
  const f32x2 th23 = rc23*-2.0f + 1.0f;
  const f32x2 om01 = 1.0f - rc01, om23 = 1.0f - rc23;
  const f32x2 sv01 = (rc01*g4)*om01, sv23 = (rc23*g4)*om23;
  const int el0=q*4;
  hdst[(el0+0)*72+jw]=f2bf1(th01[0]);
  hdst[(el0+1)*72+jw]=f2bf1(th01[1]);
  hdst[(el0+2)*72+jw]=f2bf1(th23[0]);
  hdst[(el0+3)*72+jw]=f2bf1(th23[1]);
  sdstf[(el0+0)*76+jw]=sv01[0];
  sdstf[(el0+1)*76+jw]=sv01[1];
  sdstf[(el0+2)*76+jw]=sv23[0];
  sdstf[(el0+3)*76+jw]=sv23[1];
}

// R15: plateau-confirmation probe on top of R14 (150.5us counter).
// (1) L0 merged to ONE K=32 MFMA: A-slots k0-15 = xh, k16-31 = xl (fused
//     xhl[2] array, branchless addressing); B-slots k16-31 duplicate k0-15
//     (w0t[(q&1)*8]). Sum identical to the old hi+lo MFMA pair. -1 MFMA,
//     -zero-frag setup, -exec-masked branch.
// (2) SB0 fence only BETWEEN els (el<3): tail overlaps RK4/loop-around.
// Pre-committed: <2% gain or regression => structural plateau (VALU-issue
// floor, 86% combined pipe issue, barrier drain at 3 waves/SIMD; occupancy
// toolchain-capped; conflicts at b128 floor; spill eliminated).
__global__ __launch_bounds__(256,3) void traj_kernel(Params p){
  __shared__ __align__(16) float w0f[DD][76];              // W0[a][i] f32, padded
  __shared__ __align__(16) float w3tt[HH][20];             // W3[j][a] fp32 (trace)
  __shared__ __align__(16) unsigned short w0t[HH][16];     // W0^T[jw][k<16] bf16 (L0 B-frag)
  __shared__ __align__(16) unsigned short b3f[2][64][8];   // L3 B-frags (lane-only)
  __shared__ __align__(16) unsigned short w2tf[2][4][64][8]; // GEMM2 B-frags, pi-permuted k
  __shared__ __align__(16) float4 lscA[3][64];             // {g,gb,hb,b} per col, layers 0-2
  __shared__ __align__(16) float4 lsc3[16];                // layer 3 (by m)
  __shared__ __align__(16) unsigned short xhl[2][DD][16];  // x hi/lo bf16 (fused planes)
  __shared__ __align__(16) unsigned short hbh[2][EPB][72]; // bf16 activations (ping-pong)
  __shared__ __align__(16) float sb0f[EPB][76];            // s0 f32, padded
  __shared__ __align__(16) float sb1f[EPB][76];            // s1 f32, padded
  __shared__ __align__(16) float sb2f[EPB][76];            // s2 f32, padded
  __shared__ __align__(16) float sig3w[4][DD];
  __shared__ __align__(16) float dxs[4][4][17];            // per-wave dx slice [wv][r][m]

  const int tid = threadIdx.x;
  const int e   = tid>>4;
  const int a   = tid&15;
  const int wv  = tid>>6;
  const int lane= tid&63;
  const int m   = lane&15;
  const int q   = lane>>4;
  const int b   = blockIdx.x*EPB + e;
  const int jw  = wv*16 + m;     // forward output column of this lane

  // ---- persistent register weight fragments ----
  short8 f1fr[2], f2fr[2];
  short8 w1gA[4][2];   // A-operand of W1^T tile g: lane holds W1[k=kk*32+q*8+j][g*16+m]
  {
    #pragma unroll
    for(int kk=0;kk<2;++kk){
      #pragma unroll
      for(int j=0;j<8;++j){
        const int k=kk*32+q*8+j;
        f1fr[kk][j]=(short)f2bf(p.W1[k*HH+jw]);
        f2fr[kk][j]=(short)f2bf(p.W2[k*HH+jw]);
      }
      #pragma unroll
      for(int g=0;g<4;++g){
        #pragma unroll
        for(int j=0;j<8;++j){
          const int k=kk*32+q*8+j;
          w1gA[g][kk][j]=(short)f2bf(p.W1[k*HH + g*16 + m]);
        }
      }
    }
  }

  // ---- one-time LDS staging ----
  for(int idx=tid; idx<DD*HH; idx+=256) w0f[idx>>6][idx&63]=p.W0[idx];    // f32
  for(int idx=tid; idx<HH*DD; idx+=256) w3tt[idx>>4][idx&15]=p.W3[idx];   // fp32
  for(int idx=tid; idx<HH*16; idx+=256){
    const int c_=idx>>4, k=idx&15;
    w0t[c_][k]=f2bf(p.W0[k*HH+c_]);
  }
  for(int idx=tid; idx<1024; idx+=256){
    const int kk=idx>>9, ln=(idx>>3)&63, j=idx&7;
    const int k=kk*32+(ln>>4)*8+j;
    b3f[kk][ln][j]=f2bf(p.W3[k*DD+(ln&15)]);
  }
  for(int idx=tid; idx<4096; idx+=256){       // GEMM2 B-frags with pi k-order
    const int j=idx&7, ln=(idx>>3)&63, nt=(idx>>9)&3, kk=idx>>11;
    const int qq=(ln>>4)&3;
    const int t=kk*8+j;
    const int k=16*(t>>2) + 4*qq + (t&3);      // pi(kk,q,j) = 16g+4q+r
    w2tf[kk][nt][ln][j]=f2bf(p.W2[k*HH+4*(ln&15)+nt]);
  }
  if(tid<64)            lscA[0][tid]    =make_float4(p.g0[tid],p.gb0[tid],p.hb0[tid],p.b0[tid]);
  else if(tid<128)      lscA[1][tid-64] =make_float4(p.g1[tid-64],p.gb1[tid-64],p.hb1[tid-64],p.b1[tid-64]);
  else if(tid<192)      lscA[2][tid-128]=make_float4(p.g2[tid-128],p.gb2[tid-128],p.hb2[tid-128],p.b2[tid-128]);
  else if(tid<208)      lsc3[tid-192]   =make_float4(p.g3[tid-192],p.gb3[tid-192],p.hb3[tid-192],p.b3[tid-192]);
  __syncthreads();

  float zbx = p.x0[b*DD+a];
  p.out[b*DD+a]=zbx;
  float trp[4]={0.f,0.f,0.f,0.f};
  float dvp=0.f;

  #pragma unroll 1
  for(int step=0; step<2; ++step){
    const float t0=p.ts[step], t1=p.ts[step+1];
    const float hs=t1-t0;
    float dzx=0.f;
    float zwx=zbx;
    #pragma unroll 1
    for(int stage=0; stage<4; ++stage){
      const float cin=(stage==0)?0.f:((stage==3)?1.f:0.5f);
      const float tcur=t0+cin*hs;
      const float wg=(stage==0||stage==3)?1.f:2.f;
      const float fs=hs*(1.f/6.f)*wg;
      const float fs5=0.5f*fs;

      // producer writes x as pre-split hi/lo bf16 (fused planes)
      {
        const unsigned ux=__float_as_uint(zwx);
        xhl[0][e][a]=(unsigned short)(ux>>16);
        xhl[1][e][a]=f2bf1(zwx-__uint_as_float(ux&0xFFFF0000u));
      }
      __syncthreads();                       // B1

      // ---------- L0: X @ W0, single K=32 MFMA (hi|lo packed in A-slots) ----------
      float4 sc0=lscA[0][jw];
      f32x4 c={sc0.w,sc0.w,sc0.w,sc0.w};
      {
        const short8 f0fr=*reinterpret_cast<const short8*>(&w0t[jw][(q&1)*8]);
        const short8 ax  =*reinterpret_cast<const short8*>(&xhl[q>>1][m][(q&1)*8]);
        c=MFMA(ax,f0fr,c);
      }
      fwd_epi0(c,tcur,sc0,&hbh[0][0][0],&sb0f[0][0],jw,q);
      __syncthreads();                       // B2

      // ---------- L1 ----------
      float4 sc1=lscA[1][jw];
      c=f32x4{sc1.w,sc1.w,sc1.w,sc1.w};
      #pragma unroll
      for(int kk=0;kk<2;++kk){
        const short8 ah=*reinterpret_cast<const short8*>(&hbh[0][m][kk*32+q*8]);
        c=MFMA(ah,f1fr[kk],c);
      }
      fwd_epi0(c,tcur,sc1,&hbh[1][0][0],&sb1f[0][0],jw,q);
      __syncthreads();                       // B3

      // ---------- L2 ----------
      float4 sc2=lscA[2][jw];
      c=f32x4{sc2.w,sc2.w,sc2.w,sc2.w};
      #pragma unroll
      for(int kk=0;kk<2;++kk){
        const short8 ah=*reinterpret_cast<const short8*>(&hbh[1][m][kk*32+q*8]);
        c=MFMA(ah,f2fr[kk],c);
      }
      fwd_epi0(c,tcur,sc2,&hbh[0][0][0],&sb2f[0][0],jw,q);  // h2 -> buf0
      __syncthreads();                       // B4

      // ---------- L3: dx ----------
      float4 sc3=lsc3[m];
      c=f32x4{sc3.w,sc3.w,sc3.w,sc3.w};
      #pragma unroll
      for(int kk=0;kk<2;++kk){
        const short8 bf3=*reinterpret_cast<const short8*>(&b3f[kk][lane][0]);
        const short8 ah=*reinterpret_cast<const short8*>(&hbh[0][m][kk*32+q*8]);
        c=MFMA(ah,bf3,c);
      }
      const float gate3=sigm(tcur*sc3.x+sc3.y);
      const float tb3=tcur*sc3.z;
      if(q==wv){
        #pragma unroll
        for(int r=0;r<4;++r)
          dxs[wv][r][m]=c[r]*gate3+tb3;
      }
      if(q==0) sig3w[wv][m]=gate3;
      WV();
      const float dxk=dxs[wv][q][m];         // = dx[e][a]
      dvp += fs5*dxk*dxk;

      // ---------- trace factors (once per stage, pk) ----------
      f32x2 tf2[4][2];
      {
        const f32x4 sg4=*reinterpret_cast<const f32x4*>(&sig3w[wv][q*4]);
        const f32x2 sgA={sg4[0],sg4[1]}, sgB={sg4[2],sg4[3]};
        #pragma unroll
        for(int nt=0;nt<4;++nt){
          const f32x4 w4=*reinterpret_cast<const f32x4*>(&w3tt[4*m+nt][q*4]);
          tf2[nt][0]=sgA*f32x2{w4[0],w4[1]};
          tf2[nt][1]=sgB*f32x2{w4[2],w4[3]};
        }
      }

      // ---------- tangent per element: vt-free, g-paired, el-fenced ----------
      #pragma unroll
      for(int el=0; el<4; ++el){
        const int ee=wv*4+el;
        // A0 = W0 (f32) ⊙ s0 (f32) -> bf16 pack; no unpacking
        Frag a0[2];
        #pragma unroll
        for(int kk=0;kk<2;++kk){
          const f32x4 wa=*reinterpret_cast<const f32x4*>(&w0f[m][kk*32+q*8]);
          const f32x4 wb=*reinterpret_cast<const f32x4*>(&w0f[m][kk*32+q*8+4]);
          const f32x4 sa=*reinterpret_cast<const f32x4*>(&sb0f[ee][kk*32+q*8]);
          const f32x4 sc_=*reinterpret_cast<const f32x4*>(&sb0f[ee][kk*32+q*8+4]);
          a0[kk].d[0]=pk2bf(wa[0]*sa[0], wa[1]*sa[1]);
          a0[kk].d[1]=pk2bf(wa[2]*sa[2], wa[3]*sa[3]);
          a0[kk].d[2]=pk2bf(wb[0]*sc_[0], wb[1]*sc_[1]);
          a0[kk].d[3]=pk2bf(wb[2]*sc_[2], wb[3]*sc_[3]);
        }
        // GEMM1 transposed in g-PAIRS; s1 as aligned f32x4 (broadcast reads)
        Frag a2[2];
        #pragma unroll
        for(int gp=0; gp<2; ++gp){
          f32x4 dtA={0,0,0,0}, dtB={0,0,0,0};
          #pragma unroll
          for(int kk=0;kk<2;++kk){
            dtA=MFMA(w1gA[2*gp  ][kk], a0[kk].s, dtA);
            dtB=MFMA(w1gA[2*gp+1][kk], a0[kk].s, dtB);
          }
          {
            const f32x4 s=*reinterpret_cast<const f32x4*>(&sb1f[ee][(2*gp)*16+4*q]);
            const f32x4 v=dtA*s;
            a2[gp].d[0]=pk2bf(v[0],v[1]);
            a2[gp].d[1]=pk2bf(v[2],v[3]);
          }
          {
            const f32x4 s=*reinterpret_cast<const f32x4*>(&sb1f[ee][(2*gp+1)*16+4*q]);
            const f32x4 v=dtB*s;
            a2[gp].d[2]=pk2bf(v[0],v[1]);
            a2[gp].d[3]=pk2bf(v[2],v[3]);
          }
        }
        // GEMM2 in nt pairs, B-frags streamed from LDS (pi-matched table)
        float tr=0.f;
        #pragma unroll
        for(int np=0; np<2; ++np){
          f32x4 cA={0,0,0,0}, cB={0,0,0,0};
          #pragma unroll
          for(int kk=0;kk<2;++kk){
            const short8 bA=*reinterpret_cast<const short8*>(&w2tf[kk][2*np  ][lane][0]);
            const short8 bB=*reinterpret_cast<const short8*>(&w2tf[kk][2*np+1][lane][0]);
            cA=MFMA(a2[kk].s,bA,cA);
            cB=MFMA(a2[kk].s,bB,cB);
          }
          const f32x2 s2v=*reinterpret_cast<const f32x2*>(&sb2f[ee][4*m+2*np]);
          const f32x2 tA = f32x2{cA[0],cA[1]}*tf2[2*np  ][0] + f32x2{cA[2],cA[3]}*tf2[2*np  ][1];
          const f32x2 tB = f32x2{cB[0],cB[1]}*tf2[2*np+1][0] + f32x2{cB[2],cB[3]}*tf2[2*np+1][1];
          tr += (tA[0]+tA[1])*s2v[0] + (tB[0]+tB[1])*s2v[1];
        }
        trp[el] += fs*tr;
        if(el<3) SB0();                      // fence between els only
      }

      // ---------- RK4 state update ----------
      dzx += fs*dxk;
      const float cn=(stage==2)?1.f:0.5f;
      if(stage<3) zwx=zbx+cn*hs*dxk;
    }
    zbx += dzx;
    p.out[(step+1)*(NB*DD)+b*DD+a]=zbx;
  }

  // ---------- deferred reductions ----------
  #pragma unroll
  for(int el=0; el<4; ++el){
    float v=trp[el];
    #pragma unroll
    for(int mk=32;mk>=1;mk>>=1) v+=__shfl_xor(v,mk,64);
    if(lane==el) p.out[3*NB*DD + blockIdx.x*EPB + wv*4 + el]=v;
  }
  {
    float v=dvp;
    #pragma unroll
    for(int mk=8;mk>=1;mk>>=1) v+=__shfl_xor(v,mk,16);
    if(a==0){
      p.out[3*NB*DD+NB+b]=fabsf(v);
      p.out[3*NB*DD+2*NB+b]=0.f;
    }
  }
}

extern "C" void kernel_launch(void* const* d_in, const int* in_sizes, int n_in,
                              void* d_out, int out_size, void* d_ws, size_t ws_size,
                              hipStream_t stream){
  Params p;
  p.ts  = (const float*)d_in[0];
  p.x0  = (const float*)d_in[1];
  p.W0  = (const float*)d_in[2];  p.b0 =(const float*)d_in[3];
  p.g0  = (const float*)d_in[4];  p.gb0=(const float*)d_in[5];  p.hb0=(const float*)d_in[6];
  p.W1  = (const float*)d_in[7];  p.b1 =(const float*)d_in[8];
  p.g1  = (const float*)d_in[9];  p.gb1=(const float*)d_in[10]; p.hb1=(const float*)d_in[11];
  p.W2  = (const float*)d_in[12]; p.b2 =(const float*)d_in[13];
  p.g2  = (const float*)d_in[14]; p.gb2=(const float*)d_in[15]; p.hb2=(const float*)d_in[16];
  p.W3  = (const float*)d_in[17]; p.b3 =(const float*)d_in[18];
  p.g3  = (const float*)d_in[19]; p.gb3=(const float*)d_in[20]; p.hb3=(const float*)d_in[21];
  p.out = (float*)d_out;
  hipLaunchKernelGGL(traj_kernel, dim3(NB/EPB), dim3(256), 0, stream, p);
}